// Round 6
// baseline (5944.108 us; speedup 1.0000x reference)
//
#include <hip/hip_runtime.h>

#define NB 64
#define NPTS 500
#define ND 2048
#define NK 10
#define NITERS 10
#define FEPS 1e-6f
#define PPB 125              // points per block (NPTS / 4 point-groups)
#define ACCN (4 * NK * 512)  // component-plane LDS accumulator floats (20480 = 80 KB)

// ---------------------------------------------------------------------------
// init: block per (b,k): copy f[b,k,:] -> cent, compute cnorm, zero sums row
// (atomic layout only), zero counts.
// ---------------------------------------------------------------------------
__global__ __launch_bounds__(256) void init_kernel(const float* __restrict__ f,
                                                   float* __restrict__ cent,
                                                   float* __restrict__ cnorm,
                                                   int* __restrict__ counts,
                                                   float* __restrict__ sums,
                                                   int useAtomic)
{
    const int bid = blockIdx.x;          // 0..639
    const int b = bid / NK, k = bid - b * NK;
    const int tid = threadIdx.x, wave = tid >> 6, lane = tid & 63;

    const float4* src = (const float4*)(f + ((size_t)b * NPTS + k) * ND);
    float4* dst = (float4*)cent + (size_t)bid * 512;
    float4* srow = (float4*)sums + (size_t)bid * 512;
    const float4 z4 = make_float4(0.f, 0.f, 0.f, 0.f);

    float nrm = 0.f;
    for (int i = tid; i < 512; i += 256) {
        float4 v = src[i];
        dst[i] = v;
        nrm += v.x * v.x + v.y * v.y + v.z * v.z + v.w * v.w;
        if (useAtomic) srow[i] = z4;
    }
#pragma unroll
    for (int off = 32; off > 0; off >>= 1) nrm += __shfl_xor(nrm, off, 64);
    __shared__ float red[4];
    if (lane == 0) red[wave] = nrm;
    __syncthreads();
    if (tid == 0) cnorm[bid] = red[0] + red[1] + red[2] + red[3];

    int gid = bid * 256 + tid;
    if (gid < NITERS * NB * NK) counts[gid] = 0;
}

// ---------------------------------------------------------------------------
// fused assign+update: grid (4 point-groups, NB), 512 threads (8 waves).
// Each wave handles 4 points per sweep, 4 sweeps (8w*4p*4s = 128 >= 125).
// 4 pts/wave-sweep halves centroid L2 traffic vs 2 pts (16 FMA per 16B load).
// All 40 dot partials reduced in ONE interleaved butterfly (40 indep chains).
// Rows (kept in registers) are LDS-atomic-accumulated into component planes,
// flushed as deterministic per-block partials or global fp atomics.
// ---------------------------------------------------------------------------
__global__ __launch_bounds__(512, 2) void fused_kernel(const float* __restrict__ f,
                                                       const float* __restrict__ cent,
                                                       const float* __restrict__ cnorm,
                                                       int* __restrict__ assignG,
                                                       int* __restrict__ counts_it,
                                                       float* __restrict__ sums,
                                                       float* __restrict__ partial,
                                                       int useAtomic)
{
    __shared__ float accP[ACCN];               // [4 comp][NK][512] = 80 KB

    const int b = blockIdx.y, pg = blockIdx.x;
    const int tid = threadIdx.x, wave = tid >> 6, lane = tid & 63;

    for (int i = tid; i < ACCN; i += 512) accP[i] = 0.f;
    __syncthreads();

    const float4* fb4 = (const float4*)(f + (size_t)b * NPTS * ND) + (size_t)pg * PPB * 512;
    const float4* c4  = (const float4*)(cent + (size_t)b * NK * ND);

    float cn[NK];
#pragma unroll
    for (int k = 0; k < NK; ++k) cn[k] = cnorm[b * NK + k];

    for (int s = 0; s < 4; ++s) {
        const int p0 = s * 32 + wave * 4;      // first of this wave's 4 points

        // ---- load 4 rows (clamped; invalid points guarded below) ----
        float4 R[4][8];
#pragma unroll
        for (int pt = 0; pt < 4; ++pt) {
            int m = p0 + pt; if (m >= PPB) m = PPB - 1;
            const float4* r = fb4 + (size_t)m * 512;
#pragma unroll
            for (int j = 0; j < 8; ++j) R[pt][j] = r[j * 64 + lane];
        }

        // ---- dots: 16 FMA per centroid float4 load ----
        float d[4][NK];
#pragma unroll
        for (int pt = 0; pt < 4; ++pt)
#pragma unroll
            for (int k = 0; k < NK; ++k) d[pt][k] = 0.f;

#pragma unroll
        for (int k = 0; k < NK; ++k) {
#pragma unroll
            for (int j = 0; j < 8; ++j) {
                float4 c = c4[k * 512 + j * 64 + lane];
#pragma unroll
                for (int pt = 0; pt < 4; ++pt) {
                    d[pt][k] = fmaf(R[pt][j].x, c.x, d[pt][k]);
                    d[pt][k] = fmaf(R[pt][j].y, c.y, d[pt][k]);
                    d[pt][k] = fmaf(R[pt][j].z, c.z, d[pt][k]);
                    d[pt][k] = fmaf(R[pt][j].w, c.w, d[pt][k]);
                }
            }
        }

        // ---- one interleaved butterfly: 40 independent 6-step chains ----
#pragma unroll
        for (int off = 1; off < 64; off <<= 1)
#pragma unroll
            for (int pt = 0; pt < 4; ++pt)
#pragma unroll
                for (int k = 0; k < NK; ++k)
                    d[pt][k] += __shfl_xor(d[pt][k], off, 64);

        // ---- per-point argmin (redundant across lanes; strict < = first-min,
        //      matching jnp.argmin), guarded writes + LDS accumulation ----
#pragma unroll
        for (int pt = 0; pt < 4; ++pt) {
            int a = 0;
            float best = 0.5f * cn[0] - d[pt][0];
#pragma unroll
            for (int k = 1; k < NK; ++k) {
                float t = 0.5f * cn[k] - d[pt][k];
                if (t < best) { best = t; a = k; }
            }
            const bool valid = (p0 + pt < PPB);
            if (valid) {
                if (lane == 0) {
                    assignG[b * NPTS + pg * PPB + p0 + pt] = a;
                    atomicAdd(&counts_it[b * NK + a], 1);
                }
#pragma unroll
                for (int j = 0; j < 8; ++j) {
                    int q = a * 512 + j * 64 + lane;   // bank = lane%32: free 2-way
                    atomicAdd(&accP[0 * 5120 + q], R[pt][j].x);
                    atomicAdd(&accP[1 * 5120 + q], R[pt][j].y);
                    atomicAdd(&accP[2 * 5120 + q], R[pt][j].z);
                    atomicAdd(&accP[3 * 5120 + q], R[pt][j].w);
                }
            }
        }
    }

    __syncthreads();

    if (useAtomic) {
        for (int e = tid; e < ACCN; e += 512) {
            int c = e / 5120, r = e - c * 5120;
            int k = r >> 9, q = r & 511;
            atomicAdd(&sums[((size_t)(b * NK + k)) * ND + q * 4 + c], accP[e]);
        }
    } else {
        float4* prow = (float4*)partial + ((size_t)(b * 4 + pg)) * NK * 512;
        for (int idx = tid; idx < NK * 512; idx += 512) {
            float4 v = make_float4(accP[0 * 5120 + idx], accP[1 * 5120 + idx],
                                   accP[2 * 5120 + idx], accP[3 * 5120 + idx]);
            prow[idx] = v;
        }
    }
}

// ---------------------------------------------------------------------------
// finalize: block per (b,k): cent = sum/max(cnt,1); cnorm = ||cent||^2.
// Atomic layout: also re-zero sums row for next iteration.
// ---------------------------------------------------------------------------
__global__ __launch_bounds__(256) void finalize_kernel(float* __restrict__ cent,
                                                       float* __restrict__ cnorm,
                                                       const int* __restrict__ counts_it,
                                                       float* __restrict__ sums,
                                                       const float* __restrict__ partial,
                                                       int useAtomic)
{
    const int bid = blockIdx.x;          // b*NK + k
    const int b = bid / NK, k = bid - b * NK;
    const int tid = threadIdx.x, wave = tid >> 6, lane = tid & 63;

    const float cnt = fmaxf((float)counts_it[bid], 1.f);
    float4* crow = (float4*)cent + (size_t)bid * 512;
    float4* srow = (float4*)sums + (size_t)bid * 512;
    const float4* p4 = (const float4*)partial;
    const float4 z4 = make_float4(0.f, 0.f, 0.f, 0.f);

    float nrm = 0.f;
    for (int i = tid; i < 512; i += 256) {
        float4 s;
        if (useAtomic) {
            s = srow[i];
            srow[i] = z4;
        } else {
            float4 p0 = p4[((size_t)(b * 4 + 0) * NK + k) * 512 + i];
            float4 p1 = p4[((size_t)(b * 4 + 1) * NK + k) * 512 + i];
            float4 p2 = p4[((size_t)(b * 4 + 2) * NK + k) * 512 + i];
            float4 p3 = p4[((size_t)(b * 4 + 3) * NK + k) * 512 + i];
            s = make_float4(p0.x + p1.x + p2.x + p3.x, p0.y + p1.y + p2.y + p3.y,
                            p0.z + p1.z + p2.z + p3.z, p0.w + p1.w + p2.w + p3.w);
        }
        float4 cv = make_float4(s.x / cnt, s.y / cnt, s.z / cnt, s.w / cnt);
        crow[i] = cv;
        nrm += cv.x * cv.x + cv.y * cv.y + cv.z * cv.z + cv.w * cv.w;
    }
#pragma unroll
    for (int off = 32; off > 0; off >>= 1) nrm += __shfl_xor(nrm, off, 64);
    __shared__ float red[4];
    if (lane == 0) red[wave] = nrm;
    __syncthreads();
    if (tid == 0) cnorm[bid] = red[0] + red[1] + red[2] + red[3];
}

// ---------------------------------------------------------------------------
// gem: thread per (b,d); powed cluster means ^ (1/p); empty -> centroid.
// ---------------------------------------------------------------------------
__global__ __launch_bounds__(256) void gem_kernel(const float* __restrict__ f,
                                                  const float* __restrict__ p_ptr,
                                                  const int* __restrict__ assign,
                                                  const int* __restrict__ counts_it,
                                                  const float* __restrict__ cent,
                                                  float* __restrict__ out)
{
    __shared__ int sAsn[NPTS];
    const int b = blockIdx.y;
    const int d = blockIdx.x * 256 + threadIdx.x;
    const float p = p_ptr[0];
    for (int i = threadIdx.x; i < NPTS; i += 256) sAsn[i] = assign[b * NPTS + i];
    __syncthreads();

    float acc[NK];
#pragma unroll
    for (int k = 0; k < NK; ++k) acc[k] = 0.f;

    const float* fp = f + (size_t)b * NPTS * ND + d;
#pragma unroll 2
    for (int n = 0; n < NPTS; ++n) {
        float v  = fp[(size_t)n * ND];
        float x  = fmaxf(v, FEPS);
        float pw = __expf(p * __logf(x));
        int a = sAsn[n];
#pragma unroll
        for (int k = 0; k < NK; ++k) acc[k] += (a == k) ? pw : 0.f;
    }

    const float invp = 1.f / p;
#pragma unroll
    for (int k = 0; k < NK; ++k) {
        int cnt = counts_it[b * NK + k];
        float res;
        if (cnt > 0) {
            float mean = acc[k] / (float)cnt;
            res = __expf(invp * __logf(mean));
        } else {
            res = cent[((size_t)b * NK + k) * ND + d];
        }
        out[((size_t)b * NK + k) * ND + d] = res;
    }
}

// ---------------------------------------------------------------------------
extern "C" void kernel_launch(void* const* d_in, const int* in_sizes, int n_in,
                              void* d_out, int out_size, void* d_ws, size_t ws_size,
                              hipStream_t stream)
{
    (void)in_sizes; (void)n_in; (void)out_size;

    const float* f = (const float*)d_in[0];
    const float* p = (const float*)d_in[1];
    float* out = (float*)d_out;

    const size_t centN = (size_t)NB * NK * ND;           // 1,310,720 floats
    float* cent  = (float*)d_ws;
    float* cnorm = cent + centN;                         // 640
    int*   counts = (int*)(cnorm + NB * NK);             // 6400
    int*   assign = counts + NITERS * NB * NK;           // 32000
    float* big    = (float*)(assign + NB * NPTS);
    size_t baseB  = (size_t)((char*)big - (char*)d_ws);

    // deterministic per-block partials if ws allows (21 MB), else fp atomics
    const int useAtomic = (ws_size >= baseB + 4 * centN * sizeof(float)) ? 0 : 1;
    float* sums    = big;   // atomic layout
    float* partial = big;   // partial layout

    init_kernel<<<NB * NK, 256, 0, stream>>>(f, cent, cnorm, counts, sums, useAtomic);
    for (int it = 0; it < NITERS; ++it) {
        fused_kernel<<<dim3(4, NB), 512, 0, stream>>>(
            f, cent, cnorm, assign, counts + it * NB * NK, sums, partial, useAtomic);
        finalize_kernel<<<NB * NK, 256, 0, stream>>>(
            cent, cnorm, counts + it * NB * NK, sums, partial, useAtomic);
    }
    gem_kernel<<<dim3(ND / 256, NB), 256, 0, stream>>>(
        f, p, assign, counts + (NITERS - 1) * NB * NK, cent, out);
}